// Round 1
// baseline (71.357 us; speedup 1.0000x reference)
//
#include <hip/hip_runtime.h>
#include <math.h>

#define DIMQ 16
#define HID  128
#define SPB  16   // samples per block (4 waves x 4 samples/wave)

__global__ __launch_bounds__(256, 4)
void lag_accel_kernel(const float* __restrict__ y,    // [BATCH][32]
                      const float* __restrict__ W1,   // [128][32]
                      const float* __restrict__ b1,   // [128]
                      const float* __restrict__ w2,   // [128]
                      float* __restrict__ out,        // [BATCH][16]
                      int batch)
{
    __shared__ float W1p[HID][33];   // +1 pad: conflict-free row & col access
    __shared__ float ylds[SPB][33];
    __shared__ float b1s[HID];
    __shared__ float w2s[HID];

    const int tid = threadIdx.x;

    // Stage W1 (4096 floats), b1, w2, and this block's 16 samples of y.
    for (int i = tid; i < HID * 32; i += 256)
        W1p[i >> 5][i & 31] = W1[i];
    if (tid < HID) { b1s[tid] = b1[tid]; w2s[tid] = w2[tid]; }

    const long long s0 = (long long)blockIdx.x * SPB;
    for (int i = tid; i < SPB * 32; i += 256)
        ylds[i >> 5][i & 31] = y[s0 * 32 + i];

    __syncthreads();

    const int lane = tid & 63;
    const int wave = tid >> 6;
    const int grp  = lane >> 4;      // sample within wave
    const int j    = lane & 15;      // this lane's row/column index (0..15)
    const int smp  = wave * 4 + grp; // sample within block

    // Lane j owns row j of M = I + sum_h s_h * B_h B_h^T, and rhs_j.
    float Mrow[DIMQ];
#pragma unroll
    for (int i = 0; i < DIMQ; ++i) Mrow[i] = (i == j) ? 1.0f : 0.0f;
    float rhs = 0.0f;

    for (int hb = 0; hb < HID / 16; ++hb) {
        // ---- phase 1: lane computes hidden unit h = hb*16 + j ----
        const int hj = hb * 16 + j;
        float z = b1s[hj];
        float aqd = 0.0f;            // A_h . qdot
#pragma unroll
        for (int k = 0; k < DIMQ; ++k) {
            float a   = W1p[hj][k];
            float b   = W1p[hj][16 + k];
            float qk  = ylds[smp][k];
            float qdk = ylds[smp][16 + k];
            z   = fmaf(a, qk,  z);
            z   = fmaf(b, qdk, z);
            aqd = fmaf(a, qdk, aqd);
        }
        float t  = tanhf(z);
        float u  = w2s[hj] * (1.0f - t * t);   // w2 * sech^2
        float s  = -2.0f * t * u;              // Hessian inner weight
        float sp = s * aqd;                    // s_h * (A_h . qdot)

        // ---- phase 2: accumulate rhs and M over the 16 h's of this block ----
#pragma unroll
        for (int hh = 0; hh < 16; ++hh) {
            const int h = hb * 16 + hh;
            float uh  = __shfl(u,  hh, 16);
            float sh  = __shfl(s,  hh, 16);
            float sph = __shfl(sp, hh, 16);
            float Ahj = W1p[h][j];
            float Bhj = W1p[h][16 + j];
            rhs = fmaf(uh,   Ahj, rhs);        // + dL/dq
            rhs = fmaf(-sph, Bhj, rhs);        // - qdot . J_{q,qdot}
            float sBj = sh * Bhj;
#pragma unroll
            for (int i = 0; i < DIMQ; ++i) {
                // wave-uniform address -> scalar load (SGPR operand, off DS pipe)
                float Bhi = W1[h * 32 + 16 + i];
                Mrow[i] = fmaf(sBj, Bhi, Mrow[i]);
            }
        }
    }

    // ---- solve M x = rhs with shuffle-based Gauss-Jordan (M ~ I, no pivot) ----
#pragma unroll
    for (int k = 0; k < DIMQ; ++k) {
        float piv  = __shfl(Mrow[k], k, 16);
        float invp = 1.0f / piv;
        float scale = (j == k) ? invp : 1.0f;  // normalize row k only
#pragma unroll
        for (int i = 0; i < DIMQ; ++i) Mrow[i] *= scale;
        rhs *= scale;
        float factor = (j == k) ? 0.0f : Mrow[k];
#pragma unroll
        for (int i = 0; i < DIMQ; ++i) {
            float mki = __shfl(Mrow[i], k, 16);   // lane k's (normalized) row
            Mrow[i] = fmaf(-factor, mki, Mrow[i]);
        }
        float rk = __shfl(rhs, k, 16);
        rhs = fmaf(-factor, rk, rhs);
    }

    // M is now I; rhs holds x_j = qdotdot_j.
    out[(s0 + smp) * DIMQ + j] = rhs;
}

extern "C" void kernel_launch(void* const* d_in, const int* in_sizes, int n_in,
                              void* d_out, int out_size, void* d_ws, size_t ws_size,
                              hipStream_t stream) {
    const float* y  = (const float*)d_in[0];
    const float* W1 = (const float*)d_in[1];
    const float* b1 = (const float*)d_in[2];
    const float* w2 = (const float*)d_in[3];
    float* out = (float*)d_out;
    const int batch = in_sizes[0] / 32;          // 32768
    const int blocks = (batch + SPB - 1) / SPB;  // 2048
    lag_accel_kernel<<<blocks, 256, 0, stream>>>(y, W1, b1, w2, out, batch);
}

// Round 2
// 47.904 us; speedup vs baseline: 1.4896x; 1.4896x over previous
//
#include <hip/hip_runtime.h>
#include <math.h>

#define DIMQ 16
#define HID  128
#define SPB  32          // samples per block (8 waves x 4 samples/wave)
#define NTHREADS 512

// 4-term dot accumulate: acc += v . arr[base..base+3]
#define D4(acc, v, arr, base)                                   \
    acc = fmaf((v).x, arr[(base) + 0], acc);                    \
    acc = fmaf((v).y, arr[(base) + 1], acc);                    \
    acc = fmaf((v).z, arr[(base) + 2], acc);                    \
    acc = fmaf((v).w, arr[(base) + 3], acc);

__global__ __launch_bounds__(NTHREADS, 4)
void lag_accel_kernel(const float* __restrict__ y,    // [BATCH][32]
                      const float* __restrict__ W1,   // [128][32]
                      const float* __restrict__ b1,   // [128]
                      const float* __restrict__ w2,   // [128]
                      float* __restrict__ out,        // [BATCH][16]
                      int batch)
{
    // Row-major copy (36-pad: 16B-aligned rows, 2-way bank alias = free)
    __shared__ float W1row[HID][36];
    // Transposed copies for phase-2 column reads (132-pad: 16B-aligned)
    __shared__ float ATl[16][132];
    __shared__ float BTl[16][132];
    // per-sample u/s/sp broadcast staging
    __shared__ float usp[SPB][48];
    __shared__ float b1s[HID], w2s[HID];

    const int tid = threadIdx.x;

    for (int idx = tid; idx < HID * 32; idx += NTHREADS) {
        float v = W1[idx];
        int h = idx >> 5, k = idx & 31;
        W1row[h][k] = v;
        if (k < 16) ATl[k][h] = v;
        else        BTl[k - 16][h] = v;
    }
    if (tid < HID) { b1s[tid] = b1[tid]; w2s[tid] = w2[tid]; }

    const int wave = tid >> 6;
    const int lane = tid & 63;
    const int grp  = lane >> 4;
    const int j    = lane & 15;       // this lane's row/col index
    const int smp  = wave * 4 + grp;  // sample within block
    const long long s0 = (long long)blockIdx.x * SPB;

    // ---- y sample into registers (off the LDS pipe entirely) ----
    const float* yb = y + (s0 + smp) * 32;
    float q[DIMQ], qd[DIMQ];
    {
        const float4* y4 = (const float4*)yb;
        float4 t0 = y4[0], t1 = y4[1], t2 = y4[2], t3 = y4[3];
        float4 t4 = y4[4], t5 = y4[5], t6 = y4[6], t7 = y4[7];
        q[0]=t0.x; q[1]=t0.y; q[2]=t0.z; q[3]=t0.w;
        q[4]=t1.x; q[5]=t1.y; q[6]=t1.z; q[7]=t1.w;
        q[8]=t2.x; q[9]=t2.y; q[10]=t2.z; q[11]=t2.w;
        q[12]=t3.x; q[13]=t3.y; q[14]=t3.z; q[15]=t3.w;
        qd[0]=t4.x; qd[1]=t4.y; qd[2]=t4.z; qd[3]=t4.w;
        qd[4]=t5.x; qd[5]=t5.y; qd[6]=t5.z; qd[7]=t5.w;
        qd[8]=t6.x; qd[9]=t6.y; qd[10]=t6.z; qd[11]=t6.w;
        qd[12]=t7.x; qd[13]=t7.y; qd[14]=t7.z; qd[15]=t7.w;
    }

    __syncthreads();

    float Mrow[DIMQ];
#pragma unroll
    for (int i = 0; i < DIMQ; ++i) Mrow[i] = (i == j) ? 1.0f : 0.0f;
    float rhs = 0.0f;

#pragma unroll 1
    for (int hb = 0; hb < HID / 16; ++hb) {
        const int hj = (hb << 4) + j;

        // ---- phase 1: lane computes hidden unit hj ----
        const float* wr = &W1row[hj][0];
        const float4* wr4 = (const float4*)wr;
        float4 a0 = wr4[0], a1 = wr4[1], a2 = wr4[2], a3 = wr4[3];
        float4 c0 = wr4[4], c1 = wr4[5], c2 = wr4[6], c3 = wr4[7];

        float z = b1s[hj];
        float aqd = 0.0f;
        D4(z, a0, q, 0)  D4(z, a1, q, 4)  D4(z, a2, q, 8)  D4(z, a3, q, 12)
        D4(z, c0, qd, 0) D4(z, c1, qd, 4) D4(z, c2, qd, 8) D4(z, c3, qd, 12)
        D4(aqd, a0, qd, 0) D4(aqd, a1, qd, 4) D4(aqd, a2, qd, 8) D4(aqd, a3, qd, 12)

        // branch-free tanh: r = 2/(e^{2z}+1), t = 1-r, sech^2 = r(2-r)
        float e = __expf(2.0f * z);
        float r = 2.0f * __builtin_amdgcn_rcpf(e + 1.0f);
        float t = 1.0f - r;
        float u = w2s[hj] * (r * (2.0f - r));
        float s = -2.0f * t * u;
        float sp = s * aqd;

        usp[smp][j] = u; usp[smp][16 + j] = s; usp[smp][32 + j] = sp;
        // same-wave write->read: lockstep + compiler lgkmcnt, no barrier needed

        // ---- phase 2: accumulate rhs and M over the 16 h's of this block ----
        const int hbase = hb << 4;
#pragma unroll
        for (int g = 0; g < 4; ++g) {
            float4 av = *(const float4*)&ATl[j][hbase + 4 * g];
            float4 bv = *(const float4*)&BTl[j][hbase + 4 * g];
            float4 uv = *(const float4*)&usp[smp][4 * g];
            float4 sv = *(const float4*)&usp[smp][16 + 4 * g];
            float4 pv = *(const float4*)&usp[smp][32 + 4 * g];
            const float* Bg = W1 + (long long)(hbase + 4 * g) * 32 + 16; // uniform -> s_load

#define PH2(comp, cc)                                                    \
            {                                                            \
                rhs = fmaf(uv.comp, av.comp, rhs);                       \
                rhs = fmaf(-pv.comp, bv.comp, rhs);                      \
                float sB = sv.comp * bv.comp;                            \
                const float* Br = Bg + (cc) * 32;                        \
                _Pragma("unroll")                                        \
                for (int i = 0; i < DIMQ; ++i)                           \
                    Mrow[i] = fmaf(sB, Br[i], Mrow[i]);                  \
            }
            PH2(x, 0) PH2(y, 1) PH2(z, 2) PH2(w, 3)
#undef PH2
        }
    }

    // ---- solve M x = rhs: non-normalizing Gauss-Jordan, triangular skip ----
    float diagj = 1.0f;
#pragma unroll
    for (int k = 0; k < DIMQ; ++k) {
        float piv = __shfl(Mrow[k], k, 16);
        float invp = __builtin_amdgcn_rcpf(piv);
        invp = invp * (2.0f - piv * invp);          // 1 NR step
        float factor = Mrow[k] * invp;
        factor = (j == k) ? 0.0f : factor;
        diagj  = (j == k) ? piv : diagj;
#pragma unroll
        for (int i = k; i < DIMQ; ++i) {
            float mki = __shfl(Mrow[i], k, 16);
            Mrow[i] = fmaf(-factor, mki, Mrow[i]);
        }
        float rk = __shfl(rhs, k, 16);
        rhs = fmaf(-factor, rk, rhs);
    }
    float invd = __builtin_amdgcn_rcpf(diagj);
    invd = invd * (2.0f - diagj * invd);
    out[(s0 + smp) * DIMQ + j] = rhs * invd;
}

extern "C" void kernel_launch(void* const* d_in, const int* in_sizes, int n_in,
                              void* d_out, int out_size, void* d_ws, size_t ws_size,
                              hipStream_t stream) {
    const float* y  = (const float*)d_in[0];
    const float* W1 = (const float*)d_in[1];
    const float* b1 = (const float*)d_in[2];
    const float* w2 = (const float*)d_in[3];
    float* out = (float*)d_out;
    const int batch = in_sizes[0] / 32;          // 32768
    const int blocks = (batch + SPB - 1) / SPB;  // 1024
    lag_accel_kernel<<<blocks, NTHREADS, 0, stream>>>(y, W1, b1, w2, out, batch);
}